// Round 4
// baseline (463.323 us; speedup 1.0000x reference)
//
#include <hip/hip_runtime.h>
#include <hip/hip_bf16.h>

// out = A @ W @ B, A/B block-diagonal with 128 blocks of 64x64.
// R6: persistent-WG structure (R5) + SWAPPED mm2 (out^T = tmp^T @ A^T) so the
// MFMA D-layout yields 4 consecutive out-COLUMNS per lane -> direct float4
// nontemporal stores (16x64B per wave-instr), fixing R2/R5's ragged scalar
// store regression without any out-staging LDS or extra barriers.
//   mm1: tmp = W_ab @ B_b    (W frags from regs, B^T from persistent LDS)
//   mm2: out^T = tmp^T @ A^T (tmp^T from LDS transpose, A row-major bf16 LDS)
// 2 lgkm-only barriers/tile; W/A prefetched cross-tile (vmcnt never drained).
// LDS 27.6 KB (Bt + Tt + Al), ~100 VGPR -> 4 WG/CU.

#define D 8192
#define BS 64
#define GITER 8     // a-tiles per WG; grid = (128, 128/GITER)
#define LSTR 72     // bf16 LDS row stride (144 B: 16B-aligned, 2-way max conflict)

typedef __bf16  bf16x8 __attribute__((ext_vector_type(8)));
typedef float   f32x4  __attribute__((ext_vector_type(4)));

__device__ __forceinline__ unsigned pkbf(float lo, float hi) {
    union { __hip_bfloat162 h; unsigned u; } c;
    c.h = __float22bfloat162_rn(make_float2(lo, hi));
    return c.u;
}

__device__ __forceinline__ bf16x8 mkfrag(f32x4 lo, f32x4 hi) {
    union { unsigned u[4]; bf16x8 v; } r;
    r.u[0] = pkbf(lo[0], lo[1]);
    r.u[1] = pkbf(lo[2], lo[3]);
    r.u[2] = pkbf(hi[0], hi[1]);
    r.u[3] = pkbf(hi[2], hi[3]);
    return r.v;
}

// LDS-visibility barrier without draining the vmem queue (prefetch survives).
__device__ __forceinline__ void lds_barrier() {
    asm volatile("s_waitcnt lgkmcnt(0)" ::: "memory");
    __builtin_amdgcn_s_barrier();
    asm volatile("" ::: "memory");
}

__global__ __launch_bounds__(256, 4) void bcl_kernel(
    const float* __restrict__ W,
    const float* __restrict__ Ab,
    const float* __restrict__ Bb,
    float* __restrict__ out)
{
    __shared__ __align__(16) unsigned short Bt[BS * LSTR];  // B_b^T [n][k], persistent
    __shared__ __align__(16) unsigned short Tt[BS * LSTR];  // tmp^T [n][m], per tile
    __shared__ __align__(16) unsigned short Al[BS * LSTR];  // A_a   [r][k] bf16, per tile

    const int t  = threadIdx.x;
    const int b  = blockIdx.x;            // fixed column block
    const int a0 = blockIdx.y * GITER;    // first row block of this WG

    const int lane = t & 63;
    const int wv   = t >> 6;
    const int l16  = lane & 15;
    const int quad = lane >> 4;
    const int m0   = wv * 16;             // wave owns out-cols m0..m0+15
    const int kq   = quad * 8;            // fragment k-offset (s-half adds 32)

    // staging-pattern indices (64 rows x 64 cols, f32x4 per lane)
    const int r0 = t >> 4;                // 0..15
    const int c4 = (t & 15) << 2;         // 0,4,...,60

    // Per-lane pointers.
    const float* Wp = W   + (size_t)(a0 * BS + m0 + l16) * D + b * BS + kq; // W frag rows
    const float* Ap = Ab  + (size_t)a0 * BS * BS + r0 * BS + c4;           // A staging
    float*       Op = out + (size_t)(a0 * BS + l16) * D + b * BS + m0 + quad * 4;

    // ---- issue first tile's W (fragment layout) + A (staging layout) loads ----
    f32x4 w0 = __builtin_nontemporal_load((const f32x4*)(Wp + 0));
    f32x4 w1 = __builtin_nontemporal_load((const f32x4*)(Wp + 4));
    f32x4 w2 = __builtin_nontemporal_load((const f32x4*)(Wp + 32));
    f32x4 w3 = __builtin_nontemporal_load((const f32x4*)(Wp + 36));
    f32x4 ar0 = *(const f32x4*)(Ap + 0 * 16 * BS);
    f32x4 ar1 = *(const f32x4*)(Ap + 1 * 16 * BS);
    f32x4 ar2 = *(const f32x4*)(Ap + 2 * 16 * BS);
    f32x4 ar3 = *(const f32x4*)(Ap + 3 * 16 * BS);

    // ---- stage B^T once per WG (coalesced load, transposed bf16 writes) ----
    {
        const float* Bg = Bb + (size_t)b * BS * BS;
        #pragma unroll
        for (int i = 0; i < 4; ++i) {
            const int k = i * 16 + r0;
            f32x4 v = *(const f32x4*)(Bg + k * BS + c4);
            Bt[(c4 + 0) * LSTR + k] = (unsigned short)(pkbf(v[0], v[0]) & 0xFFFFu);
            Bt[(c4 + 1) * LSTR + k] = (unsigned short)(pkbf(v[1], v[1]) & 0xFFFFu);
            Bt[(c4 + 2) * LSTR + k] = (unsigned short)(pkbf(v[2], v[2]) & 0xFFFFu);
            Bt[(c4 + 3) * LSTR + k] = (unsigned short)(pkbf(v[3], v[3]) & 0xFFFFu);
        }
    }

    #pragma unroll 1
    for (int i = 0; i < GITER; ++i) {
        // top barrier: Bt visible (i==0); Al/Tt WAR vs previous tile's reads
        lds_barrier();

        // ---- stage A_i (row-major bf16) from prefetched regs ----
        {
            uint2 p;
            p.x = pkbf(ar0[0], ar0[1]); p.y = pkbf(ar0[2], ar0[3]);
            *(uint2*)&Al[(0 * 16 + r0) * LSTR + c4] = p;
            p.x = pkbf(ar1[0], ar1[1]); p.y = pkbf(ar1[2], ar1[3]);
            *(uint2*)&Al[(1 * 16 + r0) * LSTR + c4] = p;
            p.x = pkbf(ar2[0], ar2[1]); p.y = pkbf(ar2[2], ar2[3]);
            *(uint2*)&Al[(2 * 16 + r0) * LSTR + c4] = p;
            p.x = pkbf(ar3[0], ar3[1]); p.y = pkbf(ar3[2], ar3[3]);
            *(uint2*)&Al[(3 * 16 + r0) * LSTR + c4] = p;
        }

        // ---- convert current W tile to MFMA fragments ----
        bf16x8 waf0 = mkfrag(w0, w1);
        bf16x8 waf1 = mkfrag(w2, w3);

        // ---- prefetch next tile's W/A (stays in flight across lgkm barriers) ----
        if (i + 1 < GITER) {
            const float* Wn = Wp + (size_t)(i + 1) * BS * D;
            const float* An = Ap + (i + 1) * BS * BS;
            w0 = __builtin_nontemporal_load((const f32x4*)(Wn + 0));
            w1 = __builtin_nontemporal_load((const f32x4*)(Wn + 4));
            w2 = __builtin_nontemporal_load((const f32x4*)(Wn + 32));
            w3 = __builtin_nontemporal_load((const f32x4*)(Wn + 36));
            ar0 = *(const f32x4*)(An + 0 * 16 * BS);
            ar1 = *(const f32x4*)(An + 1 * 16 * BS);
            ar2 = *(const f32x4*)(An + 2 * 16 * BS);
            ar3 = *(const f32x4*)(An + 3 * 16 * BS);
        }

        // ---- mm1: tmp = W_ab @ B_b (W regs x Bt LDS) ----
        f32x4 acc1[4] = {};
        #pragma unroll
        for (int s = 0; s < 2; ++s) {
            const int k0 = s * 32 + kq;
            const bf16x8 wa = s ? waf1 : waf0;
            #pragma unroll
            for (int j = 0; j < 4; ++j) {
                bf16x8 bf = *(const bf16x8*)&Bt[(j * 16 + l16) * LSTR + k0];
                acc1[j] = __builtin_amdgcn_mfma_f32_16x16x32_bf16(wa, bf, acc1[j], 0, 0, 0);
            }
        }

        // ---- transpose-stage tmp^T: Tt[col][row] ----
        #pragma unroll
        for (int j = 0; j < 4; ++j) {
            uint2 p;
            p.x = pkbf(acc1[j][0], acc1[j][1]);
            p.y = pkbf(acc1[j][2], acc1[j][3]);
            *(uint2*)&Tt[(j * 16 + l16) * LSTR + m0 + quad * 4] = p;
        }
        lds_barrier();

        // ---- mm2 swapped: out^T = tmp^T @ A^T  (Aop = Tt rows, Bop = Al rows) ----
        f32x4 acc2[4] = {};
        #pragma unroll
        for (int s = 0; s < 2; ++s) {
            const int k0 = s * 32 + kq;
            bf16x8 ta = *(const bf16x8*)&Tt[(m0 + l16) * LSTR + k0];
            #pragma unroll
            for (int j = 0; j < 4; ++j) {
                bf16x8 ab = *(const bf16x8*)&Al[(j * 16 + l16) * LSTR + k0];
                acc2[j] = __builtin_amdgcn_mfma_f32_16x16x32_bf16(ta, ab, acc2[j], 0, 0, 0);
            }
        }

        // ---- direct float4 stores: acc2[j] = out[j*16+l16][m0+quad*4 .. +3] ----
        float* Or = Op + (size_t)i * BS * D;
        #pragma unroll
        for (int j = 0; j < 4; ++j) {
            f32x4 v = acc2[j];
            __builtin_nontemporal_store(v, (f32x4*)(Or + (size_t)(j * 16) * D));
        }
    }
}

extern "C" void kernel_launch(void* const* d_in, const int* in_sizes, int n_in,
                              void* d_out, int out_size, void* d_ws, size_t ws_size,
                              hipStream_t stream) {
    const float* W = (const float*)d_in[0];
    const float* A = (const float*)d_in[1];
    const float* B = (const float*)d_in[2];
    float* o = (float*)d_out;
    dim3 grid(D / BS, D / BS / GITER);   // x = b (col block), y = a-group
    bcl_kernel<<<grid, 256, 0, stream>>>(W, A, B, o);
}